// Round 1
// 849.730 us; speedup vs baseline: 1.0978x; 1.0978x over previous
//
#include <hip/hip_runtime.h>
#include <math.h>

#define D       512
#define KTOP    5
#define CHUNK   32        // refs processed per chunk
#define NB_MAIN 512       // main kernel grid blocks

typedef float f32x16 __attribute__((ext_vector_type(16)));

// ---------------------------------------------------------------------------
// Kernel 1: fused ref-norm + sims + per-block top-5.
//  block = 512 threads = 8 waves. lane l = query l (B=64 == wavefront size).
//  wave w owns d-slice [64w, 64w+64) held in 64 VGPRs per lane.
//  Ref operand is wave-uniform -> loaded via s_load_dwordx16 into SGPRs and
//  consumed as the scalar operand of v_fmac (no LDS broadcast traffic at all).
//  A light vector-load pass computes ref sumsq (norms) and warms L2 for SMEM.
//  Partial dots reduced across the 8 waves via LDS float atomics.
// ---------------------------------------------------------------------------
__global__ __launch_bounds__(512, 4) void sim_topk_kernel(
    const float* __restrict__ q, const float* __restrict__ refs,
    float* __restrict__ cand_val, int* __restrict__ cand_idx, int N)
{
  __shared__ float sim_lds[CHUNK * 64];   // 8192 B  dot accumulators
  __shared__ float inv_lds[CHUNK];        // 128 B   1/norm per ref
  __shared__ float mval[8 * KTOP * 64];   // 10240 B final in-block merge
  __shared__ int   midx[8 * KTOP * 64];   // 10240 B

  const int t = threadIdx.x;
  // readfirstlane: make the wave id uniform in the compiler's divergence
  // analysis so the ref base address is computed entirely on the SALU.
  const int w = __builtin_amdgcn_readfirstlane(t >> 6);
  const int l = t & 63;
  const int dbase = w * 64;

  // Query slice -> registers (one-time; 128 KB/block, L3-resident)
  float qreg[64];
  {
    const float* qp = q + l * D + dbase;
#pragma unroll
    for (int i = 0; i < 16; ++i) {
      float4 v = *(const float4*)(qp + 4 * i);
      qreg[4*i+0] = v.x; qreg[4*i+1] = v.y; qreg[4*i+2] = v.z; qreg[4*i+3] = v.w;
    }
  }

  float tv[KTOP]; int tix[KTOP];
#pragma unroll
  for (int j = 0; j < KTOP; ++j) { tv[j] = -INFINITY; tix[j] = 0; }

  const int nchunks = (N + CHUNK - 1) / CHUNK;
  for (int c = blockIdx.x; c < nchunks; c += gridDim.x) {
    const int base = c * CHUNK;
    __syncthreads();                       // protect LDS reuse across iterations

    // zero sim accumulators
#pragma unroll
    for (int i = 0; i < (CHUNK * 64) / 512; ++i) sim_lds[t + 512 * i] = 0.f;

    // sumsq pass: 16 threads per ref, vectorized loads (also warms L2 so the
    // scalar loads below hit L2, keeping HBM ref traffic at 1x = 102 MB)
    {
      const int rr  = t >> 4;              // ref-in-chunk 0..31
      const int sub = t & 15;
      const int g   = base + rr;
      float ss = 0.f;
      if (g < N) {
        const float* rp = refs + (size_t)g * D + sub * 4;
#pragma unroll
        for (int i = 0; i < 8; ++i) {
          float4 v = *(const float4*)(rp + 64 * i);
          ss = fmaf(v.x, v.x, ss); ss = fmaf(v.y, v.y, ss);
          ss = fmaf(v.z, v.z, ss); ss = fmaf(v.w, v.w, ss);
        }
      }
      ss += __shfl_xor(ss, 1); ss += __shfl_xor(ss, 2);
      ss += __shfl_xor(ss, 4); ss += __shfl_xor(ss, 8);
      if (sub == 0) inv_lds[rr] = 1.0f / fmaxf(sqrtf(ss), 1e-12f);
    }
    __syncthreads();

    // dot loop: per ref, 4x s_load_dwordx16 (64 SGPRs) + 64 v_fmac with the
    // ref value as the scalar operand. Zero LDS reads on the critical path.
    int rlim = N - base; if (rlim > CHUNK) rlim = CHUNK;   // guard OOB s_loads
    const unsigned long long rp0 =
        (unsigned long long)(refs + (size_t)base * D + dbase);
#pragma unroll 1   // keep one 64-SGPR ref buffer live (SGPR budget = 102)
    for (int rr = 0; rr < rlim; ++rr) {
      f32x16 ra, rb, rc, rd;
      asm volatile(
          "s_load_dwordx16 %0, %4, 0x0\n\t"
          "s_load_dwordx16 %1, %4, 0x40\n\t"
          "s_load_dwordx16 %2, %4, 0x80\n\t"
          "s_load_dwordx16 %3, %4, 0xc0\n\t"
          "s_waitcnt lgkmcnt(0)"
          : "=s"(ra), "=s"(rb), "=s"(rc), "=s"(rd)
          : "s"(rp0 + (unsigned long long)rr * (D * 4)));
      float p0 = 0.f, p1 = 0.f, p2 = 0.f, p3 = 0.f;
#pragma unroll
      for (int i = 0; i < 16; ++i) {
        p0 = fmaf(ra[i], qreg[i     ], p0);
        p1 = fmaf(rb[i], qreg[16 + i], p1);
        p2 = fmaf(rc[i], qreg[32 + i], p2);
        p3 = fmaf(rd[i], qreg[48 + i], p3);
      }
      atomicAdd(&sim_lds[rr * 64 + l], (p0 + p1) + (p2 + p3));
    }
    __syncthreads();

    // top-5 update: wave w owns refs rr == w (mod 8)
#pragma unroll
    for (int k2 = 0; k2 < CHUNK / 8; ++k2) {
      const int rr = w + 8 * k2;
      const int g  = base + rr;
      if (g < N) {
        float v = sim_lds[rr * 64 + l] * inv_lds[rr];
        int  id = g;
#pragma unroll
        for (int j = 0; j < KTOP; ++j) {
          bool gt = v > tv[j];
          float ov = tv[j]; int oi = tix[j];
          tv[j]  = gt ? v  : ov;  tix[j] = gt ? id : oi;
          v      = gt ? ov : v;   id     = gt ? oi : id;
        }
      }
    }
  }

  // in-block merge of the 8 per-wave lists
  __syncthreads();
#pragma unroll
  for (int j = 0; j < KTOP; ++j) {
    mval[(w * KTOP + j) * 64 + l] = tv[j];
    midx[(w * KTOP + j) * 64 + l] = tix[j];
  }
  __syncthreads();
  if (w == 0) {
    float bv[KTOP]; int bi[KTOP];
#pragma unroll
    for (int j = 0; j < KTOP; ++j) { bv[j] = -INFINITY; bi[j] = 0; }
    for (int s = 0; s < 8 * KTOP; ++s) {
      float v = mval[s * 64 + l]; int id = midx[s * 64 + l];
#pragma unroll
      for (int j = 0; j < KTOP; ++j) {
        bool gt = v > bv[j];
        float ov = bv[j]; int oi = bi[j];
        bv[j] = gt ? v  : ov;  bi[j] = gt ? id : oi;
        v     = gt ? ov : v;   id    = gt ? oi : id;
      }
    }
#pragma unroll
    for (int j = 0; j < KTOP; ++j) {
      cand_val[(size_t)l * (NB_MAIN * KTOP) + blockIdx.x * KTOP + j] = bv[j];
      cand_idx[(size_t)l * (NB_MAIN * KTOP) + blockIdx.x * KTOP + j] = bi[j];
    }
  }
}

// ---------------------------------------------------------------------------
// Kernel 2: per-query merge of NB_MAIN*5 candidates + image gather.
// One block per query.
// ---------------------------------------------------------------------------
__global__ __launch_bounds__(256) void merge_gather_kernel(
    const float* __restrict__ cand_val, const int* __restrict__ cand_idx,
    const float* __restrict__ imgs, float* __restrict__ out)
{
  __shared__ float lval[256 * KTOP];
  __shared__ int   lidx[256 * KTOP];
  const int qn = blockIdx.x;
  const int t  = threadIdx.x;
  const int NC = NB_MAIN * KTOP;           // 2560 candidates per query

  const float* cv = cand_val + (size_t)qn * NC;
  const int*   ci = cand_idx + (size_t)qn * NC;
  float bv[KTOP]; int bi[KTOP];
#pragma unroll
  for (int j = 0; j < KTOP; ++j) { bv[j] = -INFINITY; bi[j] = 0x7fffffff; }
  for (int i = t; i < NC; i += 256) {
    float v = cv[i]; int id = ci[i];
#pragma unroll
    for (int j = 0; j < KTOP; ++j) {
      bool gt = (v > bv[j]) || (v == bv[j] && id < bi[j]);
      float ov = bv[j]; int oi = bi[j];
      bv[j] = gt ? v  : ov;  bi[j] = gt ? id : oi;
      v     = gt ? ov : v;   id    = gt ? oi : id;
    }
  }
#pragma unroll
  for (int j = 0; j < KTOP; ++j) { lval[t*KTOP+j] = bv[j]; lidx[t*KTOP+j] = bi[j]; }
  __syncthreads();

  // tree-merge sorted-5 lists: 256 -> 1
  for (int off = 128; off >= 1; off >>= 1) {
    if (t < off) {
      float ov[KTOP]; int oi[KTOP];
      int i = 0, j = 0;
#pragma unroll
      for (int n = 0; n < KTOP; ++n) {
        float av  = lval[t * KTOP + i],  bvv = lval[(t + off) * KTOP + j];
        int   ai  = lidx[t * KTOP + i],  bii = lidx[(t + off) * KTOP + j];
        bool  ta  = (av > bvv) || (av == bvv && ai <= bii);
        ov[n] = ta ? av : bvv; oi[n] = ta ? ai : bii;
        i += ta; j += !ta;
      }
#pragma unroll
      for (int n = 0; n < KTOP; ++n) { lval[t*KTOP+n] = ov[n]; lidx[t*KTOP+n] = oi[n]; }
    }
    __syncthreads();
  }

  // gather 5 images (3072 floats each), coalesced float4 copy
#pragma unroll
  for (int j = 0; j < KTOP; ++j) {
    int id = lidx[j];   // thread 0's final list
    const float4* s   = (const float4*)(imgs + (size_t)id * 3072);
    float4*       dst = (float4*)(out + (size_t)qn * (KTOP * 3072) + j * 3072);
    for (int e = t; e < 768; e += 256) dst[e] = s[e];
  }
}

extern "C" void kernel_launch(void* const* d_in, const int* in_sizes, int n_in,
                              void* d_out, int out_size, void* d_ws, size_t ws_size,
                              hipStream_t stream) {
  const float* q    = (const float*)d_in[0];   // [64, 512]
  const float* refs = (const float*)d_in[1];   // [N, 512]
  const float* imgs = (const float*)d_in[2];   // [N, 3072]
  const int N = in_sizes[1] / D;               // 50000

  float* cand_val = (float*)d_ws;                                    // 64*NB*5 floats
  int*   cand_idx = (int*)((char*)d_ws + sizeof(float) * 64 * NB_MAIN * KTOP);

  sim_topk_kernel<<<NB_MAIN, 512, 0, stream>>>(q, refs, cand_val, cand_idx, N);
  merge_gather_kernel<<<64, 256, 0, stream>>>(cand_val, cand_idx, imgs, (float*)d_out);
}

// Round 2
// 841.684 us; speedup vs baseline: 1.1083x; 1.0096x over previous
//
#include <hip/hip_runtime.h>
#include <math.h>

#define D       512
#define KTOP    5
#define CHUNK   16        // refs processed per chunk (16 -> 32KB/block: L2-resident reread)
#define NB_MAIN 512       // main kernel grid blocks

typedef float f32x16 __attribute__((ext_vector_type(16)));

// ---------------------------------------------------------------------------
// Kernel 1: fused ref-norm + sims + per-block top-5.
//  block = 512 threads = 8 waves. lane l = query l (B=64 == wavefront size).
//  wave w owns d-slice [64w, 64w+64) held in 64 VGPRs per lane.
//  Ref operand is wave-uniform -> loaded via s_load_dwordx16 into SGPRs and
//  consumed as the scalar operand of v_fmac (no LDS broadcast traffic).
//  A vector-load pass computes ref sumsq and warms L2; CHUNK=16 keeps the
//  per-XCD active footprint ~2MB so the scalar reread stays L2-resident
//  (4 waves/SIMD only hides ~L2-hit latency; VGPR-capped occupancy).
//  Partial dots reduced across the 8 waves via LDS float atomics.
// ---------------------------------------------------------------------------
__global__ __launch_bounds__(512, 4) void sim_topk_kernel(
    const float* __restrict__ q, const float* __restrict__ refs,
    float* __restrict__ cand_val, int* __restrict__ cand_idx, int N)
{
  __shared__ float sim_lds[CHUNK * 64];   // 4096 B  dot accumulators
  __shared__ float inv_lds[CHUNK];        // 64 B    1/norm per ref
  __shared__ float mval[8 * KTOP * 64];   // 10240 B final in-block merge
  __shared__ int   midx[8 * KTOP * 64];   // 10240 B

  const int t = threadIdx.x;
  const int w = __builtin_amdgcn_readfirstlane(t >> 6);  // wave id: SALU addr calc
  const int l = t & 63;                                  // lane = query id
  const int dbase = w * 64;

  // Query slice -> registers (one-time; 128 KB/block, L2/L3-resident)
  float qreg[64];
  {
    const float* qp = q + l * D + dbase;
#pragma unroll
    for (int i = 0; i < 16; ++i) {
      float4 v = *(const float4*)(qp + 4 * i);
      qreg[4*i+0] = v.x; qreg[4*i+1] = v.y; qreg[4*i+2] = v.z; qreg[4*i+3] = v.w;
    }
  }

  float tv[KTOP]; int tix[KTOP];
#pragma unroll
  for (int j = 0; j < KTOP; ++j) { tv[j] = -INFINITY; tix[j] = 0; }

  const int nchunks = (N + CHUNK - 1) / CHUNK;
  for (int c = blockIdx.x; c < nchunks; c += gridDim.x) {
    const int base = c * CHUNK;
    __syncthreads();                       // protect LDS reuse across iterations

    // zero sim accumulators
#pragma unroll
    for (int i = 0; i < (CHUNK * 64) / 512; ++i) sim_lds[t + 512 * i] = 0.f;

    // sumsq pass: 32 threads per ref, vectorized loads (warms L2 so the
    // scalar loads below hit L2; HBM ref traffic stays 1x = 102 MB)
    {
      const int rr  = t >> 5;              // ref-in-chunk 0..15
      const int sub = t & 31;
      const int g   = base + rr;
      float ss = 0.f;
      if (g < N) {
        const float* rp = refs + (size_t)g * D + sub * 4;
#pragma unroll
        for (int i = 0; i < 4; ++i) {
          float4 v = *(const float4*)(rp + 128 * i);
          ss = fmaf(v.x, v.x, ss); ss = fmaf(v.y, v.y, ss);
          ss = fmaf(v.z, v.z, ss); ss = fmaf(v.w, v.w, ss);
        }
      }
      // reduce sumsq across the 32 staging threads (contiguous lanes)
      ss += __shfl_xor(ss, 1); ss += __shfl_xor(ss, 2);
      ss += __shfl_xor(ss, 4); ss += __shfl_xor(ss, 8); ss += __shfl_xor(ss, 16);
      if (sub == 0) inv_lds[rr] = 1.0f / fmaxf(sqrtf(ss), 1e-12f);
    }
    __syncthreads();

    // dot loop: per ref, 4x s_load_dwordx16 (64 SGPRs) + 64 v_fmac with the
    // ref value as the scalar operand. Zero LDS reads on the critical path.
    int rlim = N - base; if (rlim > CHUNK) rlim = CHUNK;   // guard OOB s_loads
    const unsigned long long rp0 =
        (unsigned long long)(refs + (size_t)base * D + dbase);
#pragma unroll 1   // keep one 64-SGPR ref buffer live (SGPR budget = 102)
    for (int rr = 0; rr < rlim; ++rr) {
      f32x16 ra, rb, rc, rd;
      asm volatile(
          "s_load_dwordx16 %0, %4, 0x0\n\t"
          "s_load_dwordx16 %1, %4, 0x40\n\t"
          "s_load_dwordx16 %2, %4, 0x80\n\t"
          "s_load_dwordx16 %3, %4, 0xc0\n\t"
          "s_waitcnt lgkmcnt(0)"
          : "=s"(ra), "=s"(rb), "=s"(rc), "=s"(rd)
          : "s"(rp0 + (unsigned long long)rr * (D * 4)));
      float p0 = 0.f, p1 = 0.f, p2 = 0.f, p3 = 0.f;
#pragma unroll
      for (int i = 0; i < 16; ++i) {
        p0 = fmaf(ra[i], qreg[i     ], p0);
        p1 = fmaf(rb[i], qreg[16 + i], p1);
        p2 = fmaf(rc[i], qreg[32 + i], p2);
        p3 = fmaf(rd[i], qreg[48 + i], p3);
      }
      atomicAdd(&sim_lds[rr * 64 + l], (p0 + p1) + (p2 + p3));
    }
    __syncthreads();

    // top-5 update: wave w owns refs rr == w (mod 8)
#pragma unroll
    for (int k2 = 0; k2 < CHUNK / 8; ++k2) {
      const int rr = w + 8 * k2;
      const int g  = base + rr;
      if (g < N) {
        float v = sim_lds[rr * 64 + l] * inv_lds[rr];
        int  id = g;
#pragma unroll
        for (int j = 0; j < KTOP; ++j) {
          bool gt = v > tv[j];
          float ov = tv[j]; int oi = tix[j];
          tv[j]  = gt ? v  : ov;  tix[j] = gt ? id : oi;
          v      = gt ? ov : v;   id     = gt ? oi : id;
        }
      }
    }
  }

  // in-block merge of the 8 per-wave lists
  __syncthreads();
#pragma unroll
  for (int j = 0; j < KTOP; ++j) {
    mval[(w * KTOP + j) * 64 + l] = tv[j];
    midx[(w * KTOP + j) * 64 + l] = tix[j];
  }
  __syncthreads();
  if (w == 0) {
    float bv[KTOP]; int bi[KTOP];
#pragma unroll
    for (int j = 0; j < KTOP; ++j) { bv[j] = -INFINITY; bi[j] = 0; }
    for (int s = 0; s < 8 * KTOP; ++s) {
      float v = mval[s * 64 + l]; int id = midx[s * 64 + l];
#pragma unroll
      for (int j = 0; j < KTOP; ++j) {
        bool gt = v > bv[j];
        float ov = bv[j]; int oi = bi[j];
        bv[j] = gt ? v  : ov;  bi[j] = gt ? id : oi;
        v     = gt ? ov : v;   id    = gt ? oi : id;
      }
    }
#pragma unroll
    for (int j = 0; j < KTOP; ++j) {
      cand_val[(size_t)l * (NB_MAIN * KTOP) + blockIdx.x * KTOP + j] = bv[j];
      cand_idx[(size_t)l * (NB_MAIN * KTOP) + blockIdx.x * KTOP + j] = bi[j];
    }
  }
}

// ---------------------------------------------------------------------------
// Kernel 2: per-query merge of NB_MAIN*5 candidates + image gather.
// One block per query.
// ---------------------------------------------------------------------------
__global__ __launch_bounds__(256) void merge_gather_kernel(
    const float* __restrict__ cand_val, const int* __restrict__ cand_idx,
    const float* __restrict__ imgs, float* __restrict__ out)
{
  __shared__ float lval[256 * KTOP];
  __shared__ int   lidx[256 * KTOP];
  const int qn = blockIdx.x;
  const int t  = threadIdx.x;
  const int NC = NB_MAIN * KTOP;           // 2560 candidates per query

  const float* cv = cand_val + (size_t)qn * NC;
  const int*   ci = cand_idx + (size_t)qn * NC;
  float bv[KTOP]; int bi[KTOP];
#pragma unroll
  for (int j = 0; j < KTOP; ++j) { bv[j] = -INFINITY; bi[j] = 0x7fffffff; }
  for (int i = t; i < NC; i += 256) {
    float v = cv[i]; int id = ci[i];
#pragma unroll
    for (int j = 0; j < KTOP; ++j) {
      bool gt = (v > bv[j]) || (v == bv[j] && id < bi[j]);
      float ov = bv[j]; int oi = bi[j];
      bv[j] = gt ? v  : ov;  bi[j] = gt ? id : oi;
      v     = gt ? ov : v;   id    = gt ? oi : id;
    }
  }
#pragma unroll
  for (int j = 0; j < KTOP; ++j) { lval[t*KTOP+j] = bv[j]; lidx[t*KTOP+j] = bi[j]; }
  __syncthreads();

  // tree-merge sorted-5 lists: 256 -> 1
  for (int off = 128; off >= 1; off >>= 1) {
    if (t < off) {
      float ov[KTOP]; int oi[KTOP];
      int i = 0, j = 0;
#pragma unroll
      for (int n = 0; n < KTOP; ++n) {
        float av  = lval[t * KTOP + i],  bvv = lval[(t + off) * KTOP + j];
        int   ai  = lidx[t * KTOP + i],  bii = lidx[(t + off) * KTOP + j];
        bool  ta  = (av > bvv) || (av == bvv && ai <= bii);
        ov[n] = ta ? av : bvv; oi[n] = ta ? ai : bii;
        i += ta; j += !ta;
      }
#pragma unroll
      for (int n = 0; n < KTOP; ++n) { lval[t*KTOP+n] = ov[n]; lidx[t*KTOP+n] = oi[n]; }
    }
    __syncthreads();
  }

  // gather 5 images (3072 floats each), coalesced float4 copy
#pragma unroll
  for (int j = 0; j < KTOP; ++j) {
    int id = lidx[j];   // thread 0's final list
    const float4* s   = (const float4*)(imgs + (size_t)id * 3072);
    float4*       dst = (float4*)(out + (size_t)qn * (KTOP * 3072) + j * 3072);
    for (int e = t; e < 768; e += 256) dst[e] = s[e];
  }
}

extern "C" void kernel_launch(void* const* d_in, const int* in_sizes, int n_in,
                              void* d_out, int out_size, void* d_ws, size_t ws_size,
                              hipStream_t stream) {
  const float* q    = (const float*)d_in[0];   // [64, 512]
  const float* refs = (const float*)d_in[1];   // [N, 512]
  const float* imgs = (const float*)d_in[2];   // [N, 3072]
  const int N = in_sizes[1] / D;               // 50000

  float* cand_val = (float*)d_ws;                                    // 64*NB*5 floats
  int*   cand_idx = (int*)((char*)d_ws + sizeof(float) * 64 * NB_MAIN * KTOP);

  sim_topk_kernel<<<NB_MAIN, 512, 0, stream>>>(q, refs, cand_val, cand_idx, N);
  merge_gather_kernel<<<64, 256, 0, stream>>>(cand_val, cand_idx, imgs, (float*)d_out);
}